// Round 12
// baseline (181.352 us; speedup 1.0000x reference)
//
#include <hip/hip_runtime.h>
#include <hip/hip_bf16.h>

#define ROWS_TOTAL 8192   // 4 * 2048
#define EMB 1024
#define HEAD 64
#define SEQ 2048
#define KSPLIT 8                // attn k-chunks (blockIdx.y)
#define KC (SEQ / KSPLIT)       // 256 keys per attn block
#define KT 64                   // keys per staged attn tile

typedef __attribute__((ext_vector_type(8))) short short8;   // 8 bf16 = 4 VGPRs
typedef __attribute__((ext_vector_type(4))) float f32x4;

#define MFMA16(a, b, c) __builtin_amdgcn_mfma_f32_16x16x32_bf16((a), (b), (c), 0, 0, 0)

static __device__ __forceinline__ unsigned short f2bf(float f) {
    union { float f; unsigned u; } v; v.f = f;
    unsigned r = v.u + 0x7fff + ((v.u >> 16) & 1);   // RNE
    return (unsigned short)(r >> 16);
}

// packed f32x2 -> bf16x2 (v_cvt_pk_bf16_f32 on gfx950): low16 = a, high16 = b
static __device__ __forceinline__ unsigned pk2(float a, float b) {
    __hip_bfloat162 h = __float22bfloat162_rn(float2{a, b});
    union { __hip_bfloat162 h; unsigned u; } v; v.h = h;
    return v.u;
}

// ---------------------------------------------------------------------------
// Kernel 0: W[1024][64] x3 -> Wf bf16 in MFMA B-FRAGMENT ORDER (R8-verified):
//   Wf[kc32][tile][ln][quad][8elt]; a wave's B-frag load = dense 1 KB.
// grid = (16 k-slabs, 3 mats) x 256.
// ---------------------------------------------------------------------------
__global__ __launch_bounds__(256) void wprep_kernel(
    const float* __restrict__ Wq, const float* __restrict__ Wk,
    const float* __restrict__ Wv, unsigned short* __restrict__ Wf)
{
    __shared__ float Tr[64][65];
    const int m  = blockIdx.y;
    const int k0 = blockIdx.x * 64;
    const float* __restrict__ W = (m == 0) ? Wq : (m == 1) ? Wk : Wv;
    const int t = threadIdx.x;

    #pragma unroll
    for (int j = 0; j < 4; ++j) {
        int flat = j * 1024 + t * 4;          // 0..4095
        int k = flat >> 6, n = flat & 63;
        float4 w4 = *(const float4*)&W[(size_t)(k0 + k) * 64 + n];
        Tr[n + 0][k] = w4.x; Tr[n + 1][k] = w4.y;
        Tr[n + 2][k] = w4.z; Tr[n + 3][k] = w4.w;
    }
    __syncthreads();

    const int n   = t >> 2;                   // col 0..63
    const int k16 = t & 3;                    // 16-k chunk within slab
    union { short8 s; unsigned u[4]; } o0, o1;
    #pragma unroll
    for (int i = 0; i < 4; ++i) {
        o0.u[i] = pk2(Tr[n][k16 * 16 + 2 * i],     Tr[n][k16 * 16 + 2 * i + 1]);
        o1.u[i] = pk2(Tr[n][k16 * 16 + 8 + 2 * i], Tr[n][k16 * 16 + 9 + 2 * i]);
    }
    const int tile = m * 4 + (n >> 4);
    const int ln   = n & 15;
    const int kc32 = (k0 >> 5) + (k16 >> 1);
    const int half = k16 & 1;
    size_t off = ((size_t)(kc32 * 12 + tile) * 16 + ln) * 32 + half * 16;
    *(short8*)&Wf[off]     = o0.s;
    *(short8*)&Wf[off + 8] = o1.s;
}

// ---------------------------------------------------------------------------
// Kernel 1: QKV projection (R8-verified, byte-identical). Block = 512
// (8 waves), grid = 512 (16 rows each). Cooperative X staging, dense Wf
// B-frags, kh pair-reduce. Q pre-scaled by 0.125*log2(e); V transposed
// through LDS to Vt[b][d][s].
// ---------------------------------------------------------------------------
__global__ __launch_bounds__(512) void qkv_mfma(
    const float* __restrict__ x, const unsigned short* __restrict__ Wf,
    const float* __restrict__ bq, const float* __restrict__ bk,
    const float* __restrict__ bv,
    unsigned short* __restrict__ Qb, unsigned short* __restrict__ Kb,
    unsigned short* __restrict__ Vt)
{
    __shared__ unsigned short Xl[16][136];     // 4.25 KB staged X (272B rows)
    __shared__ f32x4 pr[4][3][64];             // 12 KB kh=1 partials
    __shared__ unsigned short vlds[64][20];

    const int t    = threadIdx.x;
    const int w    = t >> 6;
    const int lane = t & 63;
    const int ln   = lane & 15;
    const int quad = lane >> 4;
    const int m0   = blockIdx.x * 16;
    const int cg   = w >> 1;                   // col group 0..3
    const int kh   = w & 1;                    // k sub-half

    const f32x4 zero = (f32x4){0.f, 0.f, 0.f, 0.f};
    f32x4 acc[3];
    #pragma unroll
    for (int j = 0; j < 3; ++j) acc[j] = zero;

    // staging map: thread -> (row, 4 floats), coalesced within rows
    const int srow = t >> 5;                   // 0..15
    const int scol = (t & 31) * 4;             // 0..124
    const float* __restrict__ xsrc = x + (size_t)(m0 + srow) * EMB + scol;

    for (int kt = 0; kt < EMB; kt += 128) {
        float4 xv = *(const float4*)(xsrc + kt);
        uint2 pk; pk.x = pk2(xv.x, xv.y); pk.y = pk2(xv.z, xv.w);
        *(uint2*)&Xl[srow][scol] = pk;
        __syncthreads();

        #pragma unroll
        for (int cc = 0; cc < 2; ++cc) {
            short8 af = *(const short8*)&Xl[ln][kh * 64 + cc * 32 + quad * 8];
            const int kc32 = (kt >> 5) + kh * 2 + cc;
            #pragma unroll
            for (int j = 0; j < 3; ++j) {
                const int tile = cg * 3 + j;
                short8 bf = *(const short8*)
                    (Wf + ((size_t)(kc32 * 12 + tile) * 16 + ln) * 32 + quad * 8);
                acc[j] = MFMA16(af, bf, acc[j]);
            }
        }
        __syncthreads();
    }

    if (kh == 1) {
        #pragma unroll
        for (int j = 0; j < 3; ++j) pr[cg][j][lane] = acc[j];
    }
    __syncthreads();

    if (kh == 0) {
        const float qs = 0.125f * 1.44269504f;   // softmax scale * log2(e)
        #pragma unroll
        for (int j = 0; j < 3; ++j) {
            acc[j] += pr[cg][j][lane];
            const int tile = cg * 3 + j;
            const int mat  = tile >> 2;
            const int d    = (tile & 3) * 16 + ln;
            const float* bp = (mat == 0) ? bq : (mat == 1) ? bk : bv;
            const float bias = bp[d];
            #pragma unroll
            for (int r = 0; r < 4; ++r) {
                float vfull = acc[j][r] + bias;
                int row = m0 + quad * 4 + r;
                if (mat == 0)      Qb[(size_t)row * 64 + d] = f2bf(vfull * qs);
                else if (mat == 1) Kb[(size_t)row * 64 + d] = f2bf(vfull);
                else               vlds[d][quad * 4 + r] = f2bf(vfull);
            }
        }
    }
    __syncthreads();

    if (t < 256) {   // coalesced transposed V store: Vt[b][d][s]
        const int b  = m0 >> 11;
        const int s0 = m0 & 2047;
        const int d  = t >> 2;
        const int sq = (t & 3) * 4;
        ushort4 pk = {vlds[d][sq + 0], vlds[d][sq + 1],
                      vlds[d][sq + 2], vlds[d][sq + 3]};
        *(ushort4*)&Vt[((size_t)b * 64 + d) * SEQ + s0 + sq] = pk;
    }
}

// ---------------------------------------------------------------------------
// Kernel 2: MFMA flash attention (R11-verified core: cooperative staging,
// 2 q-tiles/wave, block = 256, grid = (64,8)) + SPLIT-K ATOMIC FIXUP:
// after writing partials, release-fence + atomicAdd on cnt[qblock]; the
// last-arriving block acquire-fences, combines all 8 partials for its
// 128 q-rows (L2/L3-hot) and writes final out. reduce_kernel eliminated.
// ---------------------------------------------------------------------------
__global__ __launch_bounds__(256) void attn_mfma(
    const unsigned short* __restrict__ Qb, const unsigned short* __restrict__ Kb,
    const unsigned short* __restrict__ Vt,
    float* __restrict__ Opart, float* __restrict__ lpart,
    float* __restrict__ out, int* __restrict__ cnt)
{
    __shared__ unsigned short Kl[KT][72];        // 9.2 KB  [key][d]
    __shared__ unsigned short Vl[HEAD][72];      // 9.2 KB  [d][key] (V^T)
    __shared__ unsigned short Plds[4][32][72];   // 18.4 KB per-wave P (32 q-rows)
    __shared__ int last;

    const int t    = threadIdx.x;
    const int w    = t >> 6;
    const int lane = t & 63;
    const int ln   = lane & 15;
    const int quad = lane >> 4;

    const int c  = blockIdx.y;                   // k-chunk
    const int q0 = blockIdx.x * 128 + w * 32;    // this wave's 32 q-rows
    const int b  = blockIdx.x >> 4;              // batch (128 rows/block)

    // Q A-fragments for both q-tiles (pre-scaled in qkv)
    short8 qa0[2], qa1[2];
    #pragma unroll
    for (int qt = 0; qt < 2; ++qt) {
        const unsigned short* qbase =
            Qb + (size_t)(q0 + qt * 16 + ln) * 64 + quad * 8;
        qa0[qt] = *(const short8*)(qbase);
        qa1[qt] = *(const short8*)(qbase + 32);
    }

    const f32x4 zero = (f32x4){0.f, 0.f, 0.f, 0.f};
    f32x4 O[2][4];
    #pragma unroll
    for (int qt = 0; qt < 2; ++qt)
        #pragma unroll
        for (int j = 0; j < 4; ++j) O[qt][j] = zero;
    float lacc[2][4] = {};

    // staging: 512 dense 16B slots per matrix, 2 slots per thread
    const int r0 = t >> 3,         o0v = (t & 7) * 8;
    const int r1 = (t + 256) >> 3, o1v = ((t + 256) & 7) * 8;
    const unsigned short* Ksrc0 = Kb + ((size_t)b * SEQ + c * KC + r0) * 64 + o0v;
    const unsigned short* Ksrc1 = Kb + ((size_t)b * SEQ + c * KC + r1) * 64 + o1v;
    const unsigned short* Vsrc0 = Vt + ((size_t)b * 64 + r0) * SEQ + c * KC + o0v;
    const unsigned short* Vsrc1 = Vt + ((size_t)b * 64 + r1) * SEQ + c * KC + o1v;

    unsigned short* P = &Plds[w][0][0];

    for (int kt = 0; kt < KC; kt += KT) {
        *(short8*)&Kl[r0][o0v] = *(const short8*)(Ksrc0 + (size_t)kt * 64);
        *(short8*)&Kl[r1][o1v] = *(const short8*)(Ksrc1 + (size_t)kt * 64);
        *(short8*)&Vl[r0][o0v] = *(const short8*)(Vsrc0 + kt);
        *(short8*)&Vl[r1][o1v] = *(const short8*)(Vsrc1 + kt);
        __syncthreads();

        // ---- QK^T: 4 key-subtiles; each K-frag read feeds both q-tiles
        f32x4 s[2][4];
        #pragma unroll
        for (int sub = 0; sub < 4; ++sub) {
            short8 kb0 = *(const short8*)&Kl[sub * 16 + ln][quad * 8];
            short8 kb1 = *(const short8*)&Kl[sub * 16 + ln][32 + quad * 8];
            #pragma unroll
            for (int qt = 0; qt < 2; ++qt) {
                s[qt][sub] = MFMA16(qa0[qt], kb0, zero);
                s[qt][sub] = MFMA16(qa1[qt], kb1, s[qt][sub]);
            }
        }

        // ---- p = exp2(s); denominator; stage P (C-layout -> A-layout)
        #pragma unroll
        for (int qt = 0; qt < 2; ++qt) {
            #pragma unroll
            for (int r = 0; r < 4; ++r) {
                float p0 = __builtin_amdgcn_exp2f(s[qt][0][r]);
                float p1 = __builtin_amdgcn_exp2f(s[qt][1][r]);
                float p2 = __builtin_amdgcn_exp2f(s[qt][2][r]);
                float p3 = __builtin_amdgcn_exp2f(s[qt][3][r]);
                lacc[qt][r] += (p0 + p1) + (p2 + p3);
                unsigned u01 = pk2(p0, p1);
                unsigned u23 = pk2(p2, p3);
                unsigned short* prow = P + (qt * 16 + quad * 4 + r) * 72;
                prow[ln]      = (unsigned short)u01;
                prow[16 + ln] = (unsigned short)(u01 >> 16);
                prow[32 + ln] = (unsigned short)u23;
                prow[48 + ln] = (unsigned short)(u23 >> 16);
            }
        }
        short8 pa0[2], pa1[2];
        #pragma unroll
        for (int qt = 0; qt < 2; ++qt) {
            pa0[qt] = *(const short8*)&Plds[w][qt * 16 + ln][quad * 8];
            pa1[qt] = *(const short8*)&Plds[w][qt * 16 + ln][32 + quad * 8];
        }

        // ---- PV: 4 d-tiles; each V-frag read feeds both q-tiles
        #pragma unroll
        for (int j = 0; j < 4; ++j) {
            short8 vb0 = *(const short8*)&Vl[j * 16 + ln][quad * 8];
            short8 vb1 = *(const short8*)&Vl[j * 16 + ln][32 + quad * 8];
            #pragma unroll
            for (int qt = 0; qt < 2; ++qt) {
                O[qt][j] = MFMA16(pa0[qt], vb0, O[qt][j]);
                O[qt][j] = MFMA16(pa1[qt], vb1, O[qt][j]);
            }
        }
        __syncthreads();
    }

    // denominator: reduce across the 16 key-columns of each C tile
    #pragma unroll
    for (int m = 1; m < 16; m <<= 1) {
        #pragma unroll
        for (int qt = 0; qt < 2; ++qt)
            #pragma unroll
            for (int r = 0; r < 4; ++r) lacc[qt][r] += __shfl_xor(lacc[qt][r], m);
    }

    #pragma unroll
    for (int qt = 0; qt < 2; ++qt) {
        float* __restrict__ ob = Opart + ((size_t)c * ROWS_TOTAL + q0 + qt * 16) * 64;
        #pragma unroll
        for (int j = 0; j < 4; ++j)
            #pragma unroll
            for (int r = 0; r < 4; ++r)
                ob[(size_t)(quad * 4 + r) * 64 + j * 16 + ln] = O[qt][j][r];
        if (ln == 0) {
            #pragma unroll
            for (int r = 0; r < 4; ++r)
                lpart[(size_t)c * ROWS_TOTAL + q0 + qt * 16 + quad * 4 + r] = lacc[qt][r];
        }
    }

    // ---- split-K fixup: last-arriving block combines all 8 partials
    __threadfence();                             // release partial stores
    if (t == 0)
        last = (atomicAdd(&cnt[blockIdx.x], 1) == KSPLIT - 1);
    __syncthreads();
    if (last) {
        __threadfence();                         // acquire others' stores
        const int base = blockIdx.x * 128 * 64;  // 128 q-rows of this qblock
        #pragma unroll 4
        for (int i = t; i < 128 * 64; i += 256) {
            const int idx = base + i;
            const int row = idx >> 6;
            float osum = 0.f, lsum = 0.f;
            #pragma unroll
            for (int cc = 0; cc < KSPLIT; ++cc) {
                osum += Opart[(size_t)cc * ROWS_TOTAL * HEAD + idx];
                lsum += lpart[(size_t)cc * ROWS_TOTAL + row];
            }
            out[idx] = osum / lsum;
        }
    }
}

// ---------------------------------------------------------------------------
extern "C" void kernel_launch(void* const* d_in, const int* in_sizes, int n_in,
                              void* d_out, int out_size, void* d_ws, size_t ws_size,
                              hipStream_t stream)
{
    const float* x  = (const float*)d_in[0];
    const float* Wq = (const float*)d_in[1];
    const float* bq = (const float*)d_in[2];
    const float* Wk = (const float*)d_in[3];
    const float* bk = (const float*)d_in[4];
    const float* Wv = (const float*)d_in[5];
    const float* bv = (const float*)d_in[6];
    float* out = (float*)d_out;

    char* ws = (char*)d_ws;
    unsigned short* Qb = (unsigned short*)ws;                       // 1 MB
    unsigned short* Kb = Qb + (size_t)ROWS_TOTAL * HEAD;            // 1 MB
    unsigned short* Vt = Kb + (size_t)ROWS_TOTAL * HEAD;            // 1 MB
    unsigned short* Wf = Vt + (size_t)ROWS_TOTAL * HEAD;            // 384 KB
    float* lpart = (float*)(Wf + (size_t)3 * HEAD * EMB);           // 256 KB
    float* Opart = lpart + (size_t)KSPLIT * ROWS_TOTAL;             // 16 MB
    int*   cnt   = (int*)(Opart + (size_t)KSPLIT * ROWS_TOTAL * HEAD); // 256 B

    hipMemsetAsync(cnt, 0, 64 * sizeof(int), stream);   // capture-legal
    wprep_kernel<<<dim3(16, 3), 256, 0, stream>>>(Wq, Wk, Wv, Wf);
    qkv_mfma<<<dim3(512), 512, 0, stream>>>(x, Wf, bq, bk, bv, Qb, Kb, Vt);
    attn_mfma<<<dim3(64, KSPLIT), 256, 0, stream>>>(Qb, Kb, Vt, Opart, lpart, out, cnt);
}

// Round 13
// 120.941 us; speedup vs baseline: 1.4995x; 1.4995x over previous
//
#include <hip/hip_runtime.h>
#include <hip/hip_bf16.h>

#define ROWS_TOTAL 8192   // 4 * 2048
#define EMB 1024
#define HEAD 64
#define SEQ 2048
#define KSPLIT 8                // attn k-chunks (blockIdx.y)
#define KC (SEQ / KSPLIT)       // 256 keys per attn block
#define KT 64                   // keys per staged attn tile

typedef __attribute__((ext_vector_type(8))) short short8;   // 8 bf16 = 4 VGPRs
typedef __attribute__((ext_vector_type(4))) float f32x4;

#define MFMA16(a, b, c) __builtin_amdgcn_mfma_f32_16x16x32_bf16((a), (b), (c), 0, 0, 0)

static __device__ __forceinline__ unsigned short f2bf(float f) {
    union { float f; unsigned u; } v; v.f = f;
    unsigned r = v.u + 0x7fff + ((v.u >> 16) & 1);   // RNE
    return (unsigned short)(r >> 16);
}

// packed f32x2 -> bf16x2 (v_cvt_pk_bf16_f32 on gfx950): low16 = a, high16 = b
static __device__ __forceinline__ unsigned pk2(float a, float b) {
    __hip_bfloat162 h = __float22bfloat162_rn(float2{a, b});
    union { __hip_bfloat162 h; unsigned u; } v; v.h = h;
    return v.u;
}

// ---------------------------------------------------------------------------
// Kernel 0: W[1024][64] x3 -> Wf bf16 in MFMA B-FRAGMENT ORDER (R8-verified):
//   Wf[kc32][tile][ln][quad][8elt]; a wave's B-frag load = dense 1 KB.
// grid = (16 k-slabs, 3 mats) x 256.
// ---------------------------------------------------------------------------
__global__ __launch_bounds__(256) void wprep_kernel(
    const float* __restrict__ Wq, const float* __restrict__ Wk,
    const float* __restrict__ Wv, unsigned short* __restrict__ Wf)
{
    __shared__ float Tr[64][65];
    const int m  = blockIdx.y;
    const int k0 = blockIdx.x * 64;
    const float* __restrict__ W = (m == 0) ? Wq : (m == 1) ? Wk : Wv;
    const int t = threadIdx.x;

    #pragma unroll
    for (int j = 0; j < 4; ++j) {
        int flat = j * 1024 + t * 4;          // 0..4095
        int k = flat >> 6, n = flat & 63;
        float4 w4 = *(const float4*)&W[(size_t)(k0 + k) * 64 + n];
        Tr[n + 0][k] = w4.x; Tr[n + 1][k] = w4.y;
        Tr[n + 2][k] = w4.z; Tr[n + 3][k] = w4.w;
    }
    __syncthreads();

    const int n   = t >> 2;                   // col 0..63
    const int k16 = t & 3;                    // 16-k chunk within slab
    union { short8 s; unsigned u[4]; } o0, o1;
    #pragma unroll
    for (int i = 0; i < 4; ++i) {
        o0.u[i] = pk2(Tr[n][k16 * 16 + 2 * i],     Tr[n][k16 * 16 + 2 * i + 1]);
        o1.u[i] = pk2(Tr[n][k16 * 16 + 8 + 2 * i], Tr[n][k16 * 16 + 9 + 2 * i]);
    }
    const int tile = m * 4 + (n >> 4);
    const int ln   = n & 15;
    const int kc32 = (k0 >> 5) + (k16 >> 1);
    const int half = k16 & 1;
    size_t off = ((size_t)(kc32 * 12 + tile) * 16 + ln) * 32 + half * 16;
    *(short8*)&Wf[off]     = o0.s;
    *(short8*)&Wf[off + 8] = o1.s;
}

// ---------------------------------------------------------------------------
// Kernel 1: QKV projection, 32 ROWS/BLOCK. Block = 512 (8 waves), grid = 256.
// Per 128-k iter: X tile (32x128 fp32) cooperatively staged (dense float4
// loads inside the loop — NO reg-prefetch, that regressed in R9). Wave
// (cg = w>>1, kh = w&1) computes col-tiles cg*3..+2; each dense 1 KB Wf
// B-frag feeds TWO MFMAs (row-groups 0-15 / 16-31) — Wf L2 traffic halved
// vs R11 (196 -> 98 MB). kh=1 partials pair-reduced via LDS (union'd with
// X staging). Q pre-scaled by 0.125*log2(e); V transposed via LDS.
// ---------------------------------------------------------------------------
__global__ __launch_bounds__(512) void qkv_mfma(
    const float* __restrict__ x, const unsigned short* __restrict__ Wf,
    const float* __restrict__ bq, const float* __restrict__ bk,
    const float* __restrict__ bv,
    unsigned short* __restrict__ Qb, unsigned short* __restrict__ Kb,
    unsigned short* __restrict__ Vt)
{
    __shared__ union {
        unsigned short Xl[32][136];     // 8.5 KB staged X (272B rows)
        f32x4 pr[4][3][2][64];          // 24 KB kh=1 partials (after loop)
    } sh;
    __shared__ unsigned short vlds[64][36];

    const int t    = threadIdx.x;
    const int w    = t >> 6;
    const int lane = t & 63;
    const int ln   = lane & 15;
    const int quad = lane >> 4;
    const int m0   = blockIdx.x * 32;
    const int cg   = w >> 1;                   // col group 0..3
    const int kh   = w & 1;                    // k sub-half

    const f32x4 zero = (f32x4){0.f, 0.f, 0.f, 0.f};
    f32x4 acc[3][2];
    #pragma unroll
    for (int j = 0; j < 3; ++j) { acc[j][0] = zero; acc[j][1] = zero; }

    // staging map: thread -> (row, 8 consecutive floats)
    const int srow = t >> 4;                   // 0..31
    const int scol = (t & 15) * 8;             // 0..120
    const float* __restrict__ xsrc = x + (size_t)(m0 + srow) * EMB + scol;

    for (int kt = 0; kt < EMB; kt += 128) {
        float4 xa = *(const float4*)(xsrc + kt);
        float4 xb = *(const float4*)(xsrc + kt + 4);
        union { short8 s; unsigned u[4]; } xp;
        xp.u[0] = pk2(xa.x, xa.y); xp.u[1] = pk2(xa.z, xa.w);
        xp.u[2] = pk2(xb.x, xb.y); xp.u[3] = pk2(xb.z, xb.w);
        *(short8*)&sh.Xl[srow][scol] = xp.s;
        __syncthreads();

        #pragma unroll
        for (int cc = 0; cc < 2; ++cc) {
            short8 af0 = *(const short8*)&sh.Xl[ln][kh * 64 + cc * 32 + quad * 8];
            short8 af1 = *(const short8*)&sh.Xl[16 + ln][kh * 64 + cc * 32 + quad * 8];
            const int kc32 = (kt >> 5) + kh * 2 + cc;
            #pragma unroll
            for (int j = 0; j < 3; ++j) {
                const int tile = cg * 3 + j;
                short8 bf = *(const short8*)
                    (Wf + ((size_t)(kc32 * 12 + tile) * 16 + ln) * 32 + quad * 8);
                acc[j][0] = MFMA16(af0, bf, acc[j][0]);
                acc[j][1] = MFMA16(af1, bf, acc[j][1]);
            }
        }
        __syncthreads();
    }

    if (kh == 1) {
        #pragma unroll
        for (int j = 0; j < 3; ++j) {
            sh.pr[cg][j][0][lane] = acc[j][0];
            sh.pr[cg][j][1][lane] = acc[j][1];
        }
    }
    __syncthreads();

    if (kh == 0) {
        const float qs = 0.125f * 1.44269504f;   // softmax scale * log2(e)
        #pragma unroll
        for (int j = 0; j < 3; ++j) {
            const int tile = cg * 3 + j;
            const int mat  = tile >> 2;
            const int d    = (tile & 3) * 16 + ln;
            const float* bp = (mat == 0) ? bq : (mat == 1) ? bk : bv;
            const float bias = bp[d];
            #pragma unroll
            for (int rg = 0; rg < 2; ++rg) {
                f32x4 s = acc[j][rg];
                s += sh.pr[cg][j][rg][lane];
                #pragma unroll
                for (int r = 0; r < 4; ++r) {
                    float vfull = s[r] + bias;
                    int row = m0 + rg * 16 + quad * 4 + r;
                    if (mat == 0)      Qb[(size_t)row * 64 + d] = f2bf(vfull * qs);
                    else if (mat == 1) Kb[(size_t)row * 64 + d] = f2bf(vfull);
                    else               vlds[d][rg * 16 + quad * 4 + r] = f2bf(vfull);
                }
            }
        }
    }
    __syncthreads();

    {   // coalesced transposed V store: Vt[b][d][s], 64 d x 32 s
        const int b  = m0 >> 11;
        const int s0 = m0 & 2047;
        const int d  = t >> 3;             // 0..63
        const int sq = (t & 7) * 4;        // 0..28
        ushort4 pk = {vlds[d][sq + 0], vlds[d][sq + 1],
                      vlds[d][sq + 2], vlds[d][sq + 3]};
        *(ushort4*)&Vt[((size_t)b * 64 + d) * SEQ + s0 + sq] = pk;
    }
}

// ---------------------------------------------------------------------------
// Kernel 2: MFMA flash attention (R11-verified, byte-identical): cooperative
// staging, 2 q-tiles/wave, block = 256, grid = (64 q-blocks, 8 k-chunks).
// ---------------------------------------------------------------------------
__global__ __launch_bounds__(256) void attn_mfma(
    const unsigned short* __restrict__ Qb, const unsigned short* __restrict__ Kb,
    const unsigned short* __restrict__ Vt,
    float* __restrict__ Opart, float* __restrict__ lpart)
{
    __shared__ unsigned short Kl[KT][72];        // 9.2 KB  [key][d]
    __shared__ unsigned short Vl[HEAD][72];      // 9.2 KB  [d][key] (V^T)
    __shared__ unsigned short Plds[4][32][72];   // 18.4 KB per-wave P (32 q-rows)

    const int t    = threadIdx.x;
    const int w    = t >> 6;
    const int lane = t & 63;
    const int ln   = lane & 15;
    const int quad = lane >> 4;

    const int c  = blockIdx.y;                   // k-chunk
    const int q0 = blockIdx.x * 128 + w * 32;    // this wave's 32 q-rows
    const int b  = blockIdx.x >> 4;              // batch (128 rows/block)

    short8 qa0[2], qa1[2];
    #pragma unroll
    for (int qt = 0; qt < 2; ++qt) {
        const unsigned short* qbase =
            Qb + (size_t)(q0 + qt * 16 + ln) * 64 + quad * 8;
        qa0[qt] = *(const short8*)(qbase);
        qa1[qt] = *(const short8*)(qbase + 32);
    }

    const f32x4 zero = (f32x4){0.f, 0.f, 0.f, 0.f};
    f32x4 O[2][4];
    #pragma unroll
    for (int qt = 0; qt < 2; ++qt)
        #pragma unroll
        for (int j = 0; j < 4; ++j) O[qt][j] = zero;
    float lacc[2][4] = {};

    const int r0 = t >> 3,         o0v = (t & 7) * 8;
    const int r1 = (t + 256) >> 3, o1v = ((t + 256) & 7) * 8;
    const unsigned short* Ksrc0 = Kb + ((size_t)b * SEQ + c * KC + r0) * 64 + o0v;
    const unsigned short* Ksrc1 = Kb + ((size_t)b * SEQ + c * KC + r1) * 64 + o1v;
    const unsigned short* Vsrc0 = Vt + ((size_t)b * 64 + r0) * SEQ + c * KC + o0v;
    const unsigned short* Vsrc1 = Vt + ((size_t)b * 64 + r1) * SEQ + c * KC + o1v;

    unsigned short* P = &Plds[w][0][0];

    for (int kt = 0; kt < KC; kt += KT) {
        *(short8*)&Kl[r0][o0v] = *(const short8*)(Ksrc0 + (size_t)kt * 64);
        *(short8*)&Kl[r1][o1v] = *(const short8*)(Ksrc1 + (size_t)kt * 64);
        *(short8*)&Vl[r0][o0v] = *(const short8*)(Vsrc0 + kt);
        *(short8*)&Vl[r1][o1v] = *(const short8*)(Vsrc1 + kt);
        __syncthreads();

        f32x4 s[2][4];
        #pragma unroll
        for (int sub = 0; sub < 4; ++sub) {
            short8 kb0 = *(const short8*)&Kl[sub * 16 + ln][quad * 8];
            short8 kb1 = *(const short8*)&Kl[sub * 16 + ln][32 + quad * 8];
            #pragma unroll
            for (int qt = 0; qt < 2; ++qt) {
                s[qt][sub] = MFMA16(qa0[qt], kb0, zero);
                s[qt][sub] = MFMA16(qa1[qt], kb1, s[qt][sub]);
            }
        }

        #pragma unroll
        for (int qt = 0; qt < 2; ++qt) {
            #pragma unroll
            for (int r = 0; r < 4; ++r) {
                float p0 = __builtin_amdgcn_exp2f(s[qt][0][r]);
                float p1 = __builtin_amdgcn_exp2f(s[qt][1][r]);
                float p2 = __builtin_amdgcn_exp2f(s[qt][2][r]);
                float p3 = __builtin_amdgcn_exp2f(s[qt][3][r]);
                lacc[qt][r] += (p0 + p1) + (p2 + p3);
                unsigned u01 = pk2(p0, p1);
                unsigned u23 = pk2(p2, p3);
                unsigned short* prow = P + (qt * 16 + quad * 4 + r) * 72;
                prow[ln]      = (unsigned short)u01;
                prow[16 + ln] = (unsigned short)(u01 >> 16);
                prow[32 + ln] = (unsigned short)u23;
                prow[48 + ln] = (unsigned short)(u23 >> 16);
            }
        }
        short8 pa0[2], pa1[2];
        #pragma unroll
        for (int qt = 0; qt < 2; ++qt) {
            pa0[qt] = *(const short8*)&Plds[w][qt * 16 + ln][quad * 8];
            pa1[qt] = *(const short8*)&Plds[w][qt * 16 + ln][32 + quad * 8];
        }

        #pragma unroll
        for (int j = 0; j < 4; ++j) {
            short8 vb0 = *(const short8*)&Vl[j * 16 + ln][quad * 8];
            short8 vb1 = *(const short8*)&Vl[j * 16 + ln][32 + quad * 8];
            #pragma unroll
            for (int qt = 0; qt < 2; ++qt) {
                O[qt][j] = MFMA16(pa0[qt], vb0, O[qt][j]);
                O[qt][j] = MFMA16(pa1[qt], vb1, O[qt][j]);
            }
        }
        __syncthreads();
    }

    #pragma unroll
    for (int m = 1; m < 16; m <<= 1) {
        #pragma unroll
        for (int qt = 0; qt < 2; ++qt)
            #pragma unroll
            for (int r = 0; r < 4; ++r) lacc[qt][r] += __shfl_xor(lacc[qt][r], m);
    }

    #pragma unroll
    for (int qt = 0; qt < 2; ++qt) {
        float* __restrict__ ob = Opart + ((size_t)c * ROWS_TOTAL + q0 + qt * 16) * 64;
        #pragma unroll
        for (int j = 0; j < 4; ++j)
            #pragma unroll
            for (int r = 0; r < 4; ++r)
                ob[(size_t)(quad * 4 + r) * 64 + j * 16 + ln] = O[qt][j][r];
        if (ln == 0) {
            #pragma unroll
            for (int r = 0; r < 4; ++r)
                lpart[(size_t)c * ROWS_TOTAL + q0 + qt * 16 + quad * 4 + r] = lacc[qt][r];
        }
    }
}

// ---------------------------------------------------------------------------
// Kernel 3: combine k-split partials:  out = sum_c O_c / sum_c l_c
// (no fences — R12 showed device-scope fences cause L2 writeback storms)
// ---------------------------------------------------------------------------
__global__ __launch_bounds__(256) void reduce_kernel(
    const float* __restrict__ Opart, const float* __restrict__ lpart,
    float* __restrict__ out)
{
    const int idx = blockIdx.x * 256 + threadIdx.x;   // [0, 8192*64)
    const int r   = idx >> 6;
    float osum = 0.f, lsum = 0.f;
    #pragma unroll
    for (int c = 0; c < KSPLIT; ++c) {
        osum += Opart[(size_t)c * ROWS_TOTAL * HEAD + idx];
        lsum += lpart[(size_t)c * ROWS_TOTAL + r];
    }
    out[idx] = osum / lsum;
}

// ---------------------------------------------------------------------------
extern "C" void kernel_launch(void* const* d_in, const int* in_sizes, int n_in,
                              void* d_out, int out_size, void* d_ws, size_t ws_size,
                              hipStream_t stream)
{
    const float* x  = (const float*)d_in[0];
    const float* Wq = (const float*)d_in[1];
    const float* bq = (const float*)d_in[2];
    const float* Wk = (const float*)d_in[3];
    const float* bk = (const float*)d_in[4];
    const float* Wv = (const float*)d_in[5];
    const float* bv = (const float*)d_in[6];
    float* out = (float*)d_out;

    char* ws = (char*)d_ws;
    unsigned short* Qb = (unsigned short*)ws;                       // 1 MB
    unsigned short* Kb = Qb + (size_t)ROWS_TOTAL * HEAD;            // 1 MB
    unsigned short* Vt = Kb + (size_t)ROWS_TOTAL * HEAD;            // 1 MB
    unsigned short* Wf = Vt + (size_t)ROWS_TOTAL * HEAD;            // 384 KB
    float* lpart = (float*)(Wf + (size_t)3 * HEAD * EMB);           // 256 KB
    float* Opart = lpart + (size_t)KSPLIT * ROWS_TOTAL;             // 16 MB

    wprep_kernel<<<dim3(16, 3), 256, 0, stream>>>(Wq, Wk, Wv, Wf);
    qkv_mfma<<<dim3(256), 512, 0, stream>>>(x, Wf, bq, bk, bv, Qb, Kb, Vt);
    attn_mfma<<<dim3(64, KSPLIT), 256, 0, stream>>>(Qb, Kb, Vt, Opart, lpart);
    reduce_kernel<<<dim3((ROWS_TOTAL * HEAD) / 256), 256, 0, stream>>>(Opart, lpart, out);
}